// Round 16
// baseline (154.088 us; speedup 1.0000x reference)
//
#include <hip/hip_runtime.h>
#include <hip/hip_bf16.h>
#include <math.h>

#define LATENT 256
#define HIDDEN 512
#define NFD    64
#define MAXN   50
#define BATCH  128
#define NPAIR  2450   // 50*49
#define PTILE  64
#define NTILES 39     // ceil(2450/64)

typedef __attribute__((ext_vector_type(8))) _Float16 f16x8;
typedef __attribute__((ext_vector_type(4))) float f32x4;
typedef __attribute__((ext_vector_type(16))) float f32x16;
typedef __attribute__((ext_vector_type(4))) unsigned int u32x4;

__device__ __forceinline__ float sigmoidf_(float x) {
    return 1.0f / (1.0f + expf(-x));
}
__device__ __forceinline__ f16x8 build_e1(f16x8 ui, f16x8 uj) {
    f16x8 s = ui + uj;
    return __builtin_elementwise_max(s, (f16x8)(_Float16)0);
}
__device__ __forceinline__ u32x4 pack8(float4 a, float4 b) {
    f16x8 h;
    h[0] = (_Float16)a.x; h[1] = (_Float16)a.y;
    h[2] = (_Float16)a.z; h[3] = (_Float16)a.w;
    h[4] = (_Float16)b.x; h[5] = (_Float16)b.y;
    h[6] = (_Float16)b.z; h[7] = (_Float16)b.w;
    return __builtin_bit_cast(u32x4, h);
}

// ---------------------------------------------------------------------------
// K1 prologue, grid (272, 4). Roles by blockIdx.x:
//  x<16     : fp32 gemm 32x64 tile (m0=32*y): h1h fp16 (n0<512) / Abc (n0>=512)
//  16<=x<32 : E2 -> E2t chunk-major fp16 [kc 0-63][256 g][8]
//  x>=32    : cvts: W2->W2t chunk-major [kc][512][8];
//             W3->W3t node-chunk-major [node][kc][64][8];
//             E1i/E1j -> linear [512 h][64 k] fp16
// ---------------------------------------------------------------------------
__global__ __launch_bounds__(256) void prologue_a(
    const float* __restrict__ z,
    const float* __restrict__ W1, const float* __restrict__ b1,
    const float* __restrict__ E1, const float* __restrict__ c1,
    const float* __restrict__ E2, const float* __restrict__ W2,
    const float* __restrict__ W3,
    unsigned short* __restrict__ E2t,
    unsigned short* __restrict__ W2t,
    unsigned short* __restrict__ W3t,
    unsigned short* __restrict__ E1ih,
    unsigned short* __restrict__ E1jh,
    unsigned short* __restrict__ h1h, float* __restrict__ Abc)
{
    const int tid = threadIdx.x;

    if (blockIdx.x >= 32) {   // conversions
        int slot = (blockIdx.x - 32) * 4 + blockIdx.y;   // 0..959
        int e = (slot * 256 + tid) * 8;
        float4 a, b;
        unsigned short* dst;
        if (e < 262144) {                 // W2 [512][512] -> W2t [kc][512][8]
            int row = e >> 9, k = e & 511;
            a = *(const float4*)&W2[e];
            b = *(const float4*)&W2[e + 4];
            dst = W2t + (((k >> 3) * 512 + row) << 3);
        } else if (e < 1900544) {         // W3 [3200][512] -> W3t [node][kc][64][8]
            int l = e - 262144;
            int grow = l >> 9, k = l & 511;
            int node = grow >> 6, row = grow & 63;
            a = *(const float4*)&W3[l];
            b = *(const float4*)&W3[l + 4];
            dst = W3t + node * 32768 + (((k >> 3) * 64 + row) << 3);
        } else if (e < 1933312) {         // E1i -> linear [512][64]
            int l = e - 1900544; int row = l >> 6, col = l & 63;
            a = *(const float4*)&E1[row * 384 + 256 + col];
            b = *(const float4*)&E1[row * 384 + 260 + col];
            dst = E1ih + l;
        } else {                          // E1j -> linear [512][64]
            int l = e - 1933312; int row = l >> 6, col = l & 63;
            a = *(const float4*)&E1[row * 384 + 320 + col];
            b = *(const float4*)&E1[row * 384 + 324 + col];
            dst = E1jh + l;
        }
        *(u32x4*)dst = pack8(a, b);
        return;
    }

    if (blockIdx.x >= 16) {   // E2 -> chunk-major fp16
        int idx = ((blockIdx.x - 16) * 4 + blockIdx.y) * 256 + tid;  // 16384
        int g  = idx & 255;
        int kc = idx >> 8;
        float4 a = *(const float4*)&E2[(size_t)g * 512 + kc * 8];
        float4 b = *(const float4*)&E2[(size_t)g * 512 + kc * 8 + 4];
        *(u32x4*)(E2t + (size_t)idx * 8) = pack8(a, b);
        return;
    }

    // fp32 NT gemm, 32x64 tile, 2x4/thread
    __shared__ __align__(16) float As[16][34];
    __shared__ __align__(16) float Bs[16][68];

    const int m0 = blockIdx.y * 32;
    const int n0 = blockIdx.x * 64;          // 0..1023
    const bool isE = n0 >= 512;
    const float* Bp = isE ? E1 + (size_t)(n0 - 512) * 384 : W1 + (size_t)n0 * 256;
    const int ldb = isE ? 384 : 256;

    const int sra = tid >> 3;        // 0..31
    const int kca = (tid & 7) * 2;
    const int srb = tid >> 2;        // 0..63
    const int kcb = (tid & 3) * 4;
    const int tx = tid & 15;
    const int ty = tid >> 4;         // 0..15

    float acc[2][4] = {};

    for (int k0 = 0; k0 < 256; k0 += 16) {
        float2 a2 = *(const float2*)&z[(size_t)(m0 + sra) * 256 + k0 + kca];
        As[kca][sra] = a2.x; As[kca + 1][sra] = a2.y;
        float4 b4 = *(const float4*)&Bp[(size_t)srb * ldb + k0 + kcb];
        Bs[kcb + 0][srb] = b4.x; Bs[kcb + 1][srb] = b4.y;
        Bs[kcb + 2][srb] = b4.z; Bs[kcb + 3][srb] = b4.w;
        __syncthreads();
        #pragma unroll
        for (int k = 0; k < 16; ++k) {
            float av[2], bv[4];
            av[0] = As[k][ty * 2]; av[1] = As[k][ty * 2 + 1];
            *(float4*)bv = *(const float4*)&Bs[k][tx * 4];
            #pragma unroll
            for (int r = 0; r < 2; ++r)
                #pragma unroll
                for (int c = 0; c < 4; ++c)
                    acc[r][c] = fmaf(av[r], bv[c], acc[r][c]);
        }
        __syncthreads();
    }

    #pragma unroll
    for (int r = 0; r < 2; ++r) {
        int gm = m0 + ty * 2 + r;
        #pragma unroll
        for (int c = 0; c < 4; ++c) {
            int gn = n0 + tx * 4 + c;
            if (isE) {
                int gl = gn - 512;
                Abc[(size_t)gm * 512 + gl] = acc[r][c] + c1[gl];
            } else {
                float v = fmaxf(acc[r][c] + b1[gn], 0.f);
                h1h[(size_t)gm * 512 + gn] =
                    __builtin_bit_cast(unsigned short, (_Float16)v);
            }
        }
    }
}

// ---------------------------------------------------------------------------
// K3': fused h2 + nf + Ui/Uj.  grid (50, 2): node = x, m0 = 64y. 512 thr.
// (unchanged from R14)
// ---------------------------------------------------------------------------
__global__ __launch_bounds__(512, 1) void nfu_gemm(
    const unsigned short* __restrict__ h1h,
    const unsigned short* __restrict__ W2t,   // [kc][512][8]
    const float* __restrict__ b2,
    const unsigned short* __restrict__ W3t,   // [node][kc][64][8]
    const float* __restrict__ b3,
    const unsigned short* __restrict__ E1ih,
    const unsigned short* __restrict__ E1jh,
    const float* __restrict__ Abc,
    float* __restrict__ outN,               // [128,3200] sigmoid
    unsigned short* __restrict__ Uih,       // [128*50,512]
    unsigned short* __restrict__ Ujh)
{
    __shared__ unsigned short As[2][64 * 32];          // 8KB h1 dbuf, swizzled
    __shared__ __align__(16) unsigned short h2s[64][520];  // 66.6KB
    __shared__ __align__(16) unsigned short nft[64][72];

    const int tid = threadIdx.x;
    const int lane = tid & 63;
    const int w8 = tid >> 6;     // 0..7
    const int w  = w8 & 3;       // phases B/C wave id
    const int ln = lane & 15;
    const int hi = lane >> 4;
    const int node = blockIdx.x;
    const int m0 = blockIdx.y * 64;

    // ---- phase A ----
    const int srow = (tid & 255) >> 2;
    const int sc   = tid & 3;
    const unsigned short* gA = h1h + (size_t)(m0 + srow) * 512 + sc * 8;
    const int swr = srow * 32 + ((sc ^ ((srow >> 1) & 3)) * 8);
    const int q   = hi ^ ((ln >> 1) & 3);
    const int ard = ln * 32 + q * 8;
    const unsigned short* bB = W2t + ((size_t)hi * 512 + 64 * w8 + ln) * 8;

    f32x4 acc[4][4] = {};
    f16x8 hN = {};
    if (tid < 256) {
        f16x8 h0 = *(const f16x8*)gA;
        *(f16x8*)&As[0][swr] = h0;
        hN = *(const f16x8*)(gA + 32);
    }
    f16x8 bf[4];
    #pragma unroll
    for (int ni = 0; ni < 4; ++ni)
        bf[ni] = *(const f16x8*)(bB + ni * 128);
    asm volatile("s_waitcnt lgkmcnt(0)\n\ts_barrier" ::: "memory");

    #pragma unroll
    for (int ks = 0; ks < 16; ++ks) {
        if (tid < 256 && ks < 15)
            *(f16x8*)&As[(ks + 1) & 1][swr] = hN;
        if (tid < 256 && ks < 14)
            hN = *(const f16x8*)(gA + 32 * (ks + 2));
        f16x8 af[4];
        #pragma unroll
        for (int mi = 0; mi < 4; ++mi)
            af[mi] = *(const f16x8*)&As[ks & 1][ard + mi * 512];
        __builtin_amdgcn_s_setprio(1);
        #pragma unroll
        for (int ni = 0; ni < 4; ++ni)
            #pragma unroll
            for (int mi = 0; mi < 4; ++mi)
                acc[mi][ni] = __builtin_amdgcn_mfma_f32_16x16x32_f16(
                    af[mi], bf[ni], acc[mi][ni], 0, 0, 0);
        __builtin_amdgcn_s_setprio(0);
        if (ks < 15) {
            #pragma unroll
            for (int ni = 0; ni < 4; ++ni)
                bf[ni] = *(const f16x8*)(bB + (size_t)(ks + 1) * 16384 + ni * 128);
            asm volatile("s_waitcnt lgkmcnt(0)\n\ts_barrier" ::: "memory");
        }
    }

    // epilogue A: relu + b2 -> h2s fp16
    #pragma unroll
    for (int ni = 0; ni < 4; ++ni) {
        int col = 64 * w8 + 16 * ni + ln;
        float bias = b2[col];
        #pragma unroll
        for (int mi = 0; mi < 4; ++mi)
            #pragma unroll
            for (int r = 0; r < 4; ++r) {
                float v = fmaxf(acc[mi][ni][r] + bias, 0.f);
                h2s[16 * mi + 4 * hi + r][col] =
                    __builtin_bit_cast(unsigned short, (_Float16)v);
            }
    }
    __syncthreads();

    // ---- phase B (waves 0-3): nf = h2s @ W3t[node]^T + b3 ----
    if (w8 < 4) {
        const unsigned short* bW3 = W3t + (size_t)node * 32768 + hi * 512 + ln * 8;
        f32x4 accB[4] = {};
        #pragma unroll
        for (int ks = 0; ks < 16; ++ks) {
            f16x8 af = *(const f16x8*)&h2s[16 * w + ln][ks * 32 + hi * 8];
            f16x8 bfB[4];
            #pragma unroll
            for (int ni = 0; ni < 4; ++ni)
                bfB[ni] = *(const f16x8*)(bW3 + ks * 2048 + ni * 128);
            #pragma unroll
            for (int ni = 0; ni < 4; ++ni)
                accB[ni] = __builtin_amdgcn_mfma_f32_16x16x32_f16(
                    af, bfB[ni], accB[ni], 0, 0, 0);
        }
        #pragma unroll
        for (int ni = 0; ni < 4; ++ni) {
            int gnl = 16 * ni + ln;
            int gng = node * 64 + gnl;
            float bias = b3[gng];
            #pragma unroll
            for (int r = 0; r < 4; ++r) {
                int bl = 16 * w + 4 * hi + r;
                float v = accB[ni][r] + bias;
                outN[(size_t)(m0 + bl) * 3200 + gng] = sigmoidf_(v);
                nft[bl][gnl] = __builtin_bit_cast(unsigned short, (_Float16)v);
            }
        }
    }
    __syncthreads();

    // ---- phase C (waves 0-3): Ui/Uj (verbatim) ----
    if (w8 < 4) {
        f16x8 af2[2][4];
        #pragma unroll
        for (int ks2 = 0; ks2 < 2; ++ks2)
            #pragma unroll
            for (int mi = 0; mi < 4; ++mi)
                af2[ks2][mi] = *(const f16x8*)&nft[16 * mi + ln][ks2 * 32 + hi * 8];

        #pragma unroll
        for (int ij = 0; ij < 2; ++ij) {
            const unsigned short* Ep = ij ? E1jh : E1ih;
            unsigned short* Ud = ij ? Ujh : Uih;
            #pragma unroll
            for (int half = 0; half < 2; ++half) {
                f32x4 acc2[4][4] = {};
                #pragma unroll
                for (int ks2 = 0; ks2 < 2; ++ks2) {
                    f16x8 bf2[4];
                    #pragma unroll
                    for (int ni = 0; ni < 4; ++ni)
                        bf2[ni] = *(const f16x8*)(Ep +
                            (size_t)(128 * w + half * 64 + 16 * ni + ln) * 64 +
                            ks2 * 32 + hi * 8);
                    #pragma unroll
                    for (int ni = 0; ni < 4; ++ni)
                        #pragma unroll
                        for (int mi = 0; mi < 4; ++mi)
                            acc2[mi][ni] = __builtin_amdgcn_mfma_f32_16x16x32_f16(
                                af2[ks2][mi], bf2[ni], acc2[mi][ni], 0, 0, 0);
                }
                #pragma unroll
                for (int mi = 0; mi < 4; ++mi) {
                    #pragma unroll
                    for (int r = 0; r < 4; ++r) {
                        int batch = m0 + 16 * mi + 4 * hi + r;
                        #pragma unroll
                        for (int ni = 0; ni < 4; ++ni) {
                            int h = 128 * w + half * 64 + 16 * ni + ln;
                            float v = acc2[mi][ni][r];
                            if (ij == 0) v += Abc[(size_t)batch * 512 + h];
                            Ud[((size_t)batch * 50 + node) * 512 + h] =
                                __builtin_bit_cast(unsigned short, (_Float16)v);
                        }
                    }
                }
            }
        }
    }
}

// ---------------------------------------------------------------------------
// K4: MFMA edge kernel v13 — R12 loop structure (16 windows, 1 barrier each,
// single bf generation in flight, same swizzled A LDS + staging) with the
// 32x32x16 MFMA shape: per window 8 MFMA x 8.07cyc = 64.6 cyc vs 16 x 4.85
// = 77.6 (-17% matrix-pipe time, half the issue slots).
// A/B fragments: lane l -> row/col = l&31, k-chunk = l>>5 (k-perm cancels
// A vs B). C/D: col = lane&31, row = (reg&3)+8*(reg>>2)+4*(lane>>5) [m74].
// Grid: 1D 4992 = 8 XCD x 624, bijective swizzle.
// ---------------------------------------------------------------------------
__global__ __launch_bounds__(256, 4) void edge_mfma(
    const unsigned short* __restrict__ Ui,   // [B*50,512] fp16 (incl. Abc)
    const unsigned short* __restrict__ Uj,   // [B*50,512] fp16
    const unsigned short* __restrict__ E2t,  // [64 kc][256 g][8] fp16
    const float* __restrict__ c2,
    const float* __restrict__ E3,
    const float* __restrict__ c3p,
    float* __restrict__ outE)                // [B,2450]
{
    __shared__ unsigned short As[2][PTILE * 32];   // 8KB dbuf, swizzled
    __shared__ float c2_s[256], e3_s[256];
    __shared__ int   ii_s[PTILE], jj_s[PTILE];
    __shared__ float red[PTILE][5];

    // XCD-bijective swizzle: 4992 = 8 * 624
    const int gid = blockIdx.x;
    const int nid = (gid & 7) * 624 + (gid >> 3);
    const int b   = nid / NTILES;
    const int p0  = (nid - b * NTILES) * PTILE;

    const int tid = threadIdx.x;
    const int lane = tid & 63;
    const int wid  = tid >> 6;    // g quarter
    const int r31 = lane & 31;
    const int hb  = lane >> 5;

    c2_s[tid] = c2[tid];
    e3_s[tid] = E3[tid];
    if (tid < PTILE) {
        int p = p0 + tid;
        int i = 0, j = 0;
        if (p < NPAIR) {
            i = p / 49;
            int kk = p - i * 49;
            j = kk + (kk >= i ? 1 : 0);
        }
        ii_s[tid] = i;
        jj_s[tid] = j;
    }
    __syncthreads();

    const unsigned short* UiB = Ui + (size_t)b * MAXN * HIDDEN;
    const unsigned short* UjB = Uj + (size_t)b * MAXN * HIDDEN;

    // A staging: thread -> (row srow, chunk sc) of 64x32 tile (unchanged)
    const int srow = tid >> 2;
    const int sc   = tid & 3;
    const unsigned short* gUi = UiB + (size_t)ii_s[srow] * HIDDEN + sc * 8;
    const unsigned short* gUj = UjB + (size_t)jj_s[srow] * HIDDEN + sc * 8;
    const int swr = srow * 32 + ((sc ^ ((srow >> 1) & 3)) * 8);

    // A fragment read (swizzled): af[mh][t] at
    //   As[(32*mh + r31)*32 + (((2t+hb) ^ rowq)*8],  rowq = (r31>>1)&3
    //   (32*mh doesn't change rowq: 16 mod 4 == 0)
    const int rowq = (r31 >> 1) & 3;
    const int abase = r31 * 32;
    const int co0 = ((0 + hb) ^ rowq) * 8;   // t=0 chunk
    const int co1 = ((2 + hb) ^ rowq) * 8;   // t=1 chunk

    // B fragment global base: g = 64*wid + 32*nh + r31, kc = 4w + 2t + hb
    //   addr = E2t + kc*2048 + (64*wid + r31)*8 + nh*256
    const unsigned short* bB = E2t + (size_t)hb * 2048 + (64 * wid + r31) * 8;

    f32x16 acc[2][2] = {};

    // ---- prologue: A(0)->LDS; U(1)->regs; bf window-0 (both t) -> regs
    {
        f16x8 u0 = *(const f16x8*)gUi;
        f16x8 v0 = *(const f16x8*)gUj;
        *(f16x8*)&As[0][swr] = build_e1(u0, v0);
    }
    f16x8 uiN = *(const f16x8*)(gUi + 32);
    f16x8 ujN = *(const f16x8*)(gUj + 32);
    f16x8 bf[2][2];   // [t][nh]
    #pragma unroll
    for (int t = 0; t < 2; ++t)
        #pragma unroll
        for (int nh = 0; nh < 2; ++nh)
            bf[t][nh] = *(const f16x8*)(bB + t * 4096 + nh * 256);
    asm volatile("s_waitcnt lgkmcnt(0)\n\ts_barrier" ::: "memory");

    #pragma unroll
    for (int w = 0; w < 16; ++w) {
        // build + store A(w+1) (consumes U(w+1))
        if (w < 15)
            *(f16x8*)&As[(w + 1) & 1][swr] = build_e1(uiN, ujN);
        // prefetch U(w+2)
        if (w < 14) {
            uiN = *(const f16x8*)(gUi + 32 * (w + 2));
            ujN = *(const f16x8*)(gUj + 32 * (w + 2));
        }
        // af from LDS (post-barrier; 4 ds_read_b128)
        f16x8 af[2][2];   // [mh][t]
        #pragma unroll
        for (int mh = 0; mh < 2; ++mh) {
            af[mh][0] = *(const f16x8*)&As[w & 1][abase + mh * 1024 + co0];
            af[mh][1] = *(const f16x8*)&As[w & 1][abase + mh * 1024 + co1];
        }
        // MFMA cluster: 8 x 32x32x16 (consumes bf window w)
        __builtin_amdgcn_s_setprio(1);
        #pragma unroll
        for (int t = 0; t < 2; ++t)
            #pragma unroll
            for (int nh = 0; nh < 2; ++nh)
                #pragma unroll
                for (int mh = 0; mh < 2; ++mh)
                    acc[mh][nh] = __builtin_amdgcn_mfma_f32_32x32x16_f16(
                        af[mh][t], bf[t][nh], acc[mh][nh], 0, 0, 0);
        __builtin_amdgcn_s_setprio(0);
        // reload bf for window w+1 (issued after last MFMA read of bf)
        if (w < 15) {
            #pragma unroll
            for (int t = 0; t < 2; ++t)
                #pragma unroll
                for (int nh = 0; nh < 2; ++nh)
                    bf[t][nh] = *(const f16x8*)(bB + (size_t)(w + 1) * 8192 +
                                                t * 4096 + nh * 256);
            asm volatile("s_waitcnt lgkmcnt(0)\n\ts_barrier" ::: "memory");
        }
    }

    // ---- epilogue: relu(+c2), dot E3, 32-lane shuffle reduce, LDS combine
    const float c3v = c3p[0];
    #pragma unroll
    for (int mh = 0; mh < 2; ++mh) {
        #pragma unroll
        for (int reg = 0; reg < 16; ++reg) {
            float part = 0.f;
            #pragma unroll
            for (int nh = 0; nh < 2; ++nh) {
                int g = 64 * wid + 32 * nh + r31;
                float v = fmaxf(acc[mh][nh][reg] + c2_s[g], 0.f);
                part = fmaf(v, e3_s[g], part);
            }
            part += __shfl_xor(part, 1);
            part += __shfl_xor(part, 2);
            part += __shfl_xor(part, 4);
            part += __shfl_xor(part, 8);
            part += __shfl_xor(part, 16);
            if (r31 == 0)
                red[32 * mh + (reg & 3) + 8 * (reg >> 2) + 4 * hb][wid] = part;
        }
    }
    __syncthreads();

    if (tid < PTILE) {
        int p = p0 + tid;
        if (p < NPAIR) {
            float s = red[tid][0] + red[tid][1] + red[tid][2] + red[tid][3] + c3v;
            outE[(size_t)b * NPAIR + p] = sigmoidf_(s);
        }
    }
}

// ---------------------------------------------------------------------------
extern "C" void kernel_launch(void* const* d_in, const int* in_sizes, int n_in,
                              void* d_out, int out_size, void* d_ws, size_t ws_size,
                              hipStream_t stream)
{
    const float* z  = (const float*)d_in[0];
    const float* W1 = (const float*)d_in[1];
    const float* b1 = (const float*)d_in[2];
    const float* W2 = (const float*)d_in[3];
    const float* b2 = (const float*)d_in[4];
    const float* W3 = (const float*)d_in[5];
    const float* b3 = (const float*)d_in[6];
    const float* E1 = (const float*)d_in[7];
    const float* c1 = (const float*)d_in[8];
    const float* E2 = (const float*)d_in[9];
    const float* c2 = (const float*)d_in[10];
    const float* E3 = (const float*)d_in[11];
    const float* c3 = (const float*)d_in[12];

    float* out = (float*)d_out;
    float* ws  = (float*)d_ws;

    // workspace layout
    float* Abc = ws;                                        // 65536 f32
    unsigned short* h1h  = (unsigned short*)(Abc + 65536);  // 65536
    unsigned short* W2t  = h1h + 65536;                     // 262144
    unsigned short* W3t  = W2t + 262144;                    // 1638400
    unsigned short* E1ih = W3t + 1638400;                   // 32768
    unsigned short* E1jh = E1ih + 32768;                    // 32768
    unsigned short* E2t  = E1jh + 32768;                    // 131072
    unsigned short* Uih  = E2t + 131072;                    // 3276800
    unsigned short* Ujh  = Uih + 3276800;                   // 3276800

    dim3 blk(256);

    // K1: h1h, Abc, E2t, W2t, W3t, E1ih, E1jh
    prologue_a<<<dim3(272, 4), blk, 0, stream>>>(
        z, W1, b1, E1, c1, E2, W2, W3, E2t, W2t, W3t, E1ih, E1jh, h1h, Abc);

    // K3': fused h2 + nf (sigmoid->out) + Ui/Uj
    nfu_gemm<<<dim3(50, 2), dim3(512), 0, stream>>>(
        h1h, W2t, b2, W3t, b3, E1ih, E1jh, Abc, out, Uih, Ujh);

    // K4: fused edge MLP (1D grid, XCD-swizzled, 32x32x16 MFMA)
    edge_mfma<<<dim3(NTILES * BATCH), blk, 0, stream>>>(
        Uih, Ujh, E2t, c2, E3, c3, out + BATCH * MAXN * NFD);
}

// Round 17
// 146.257 us; speedup vs baseline: 1.0535x; 1.0535x over previous
//
#include <hip/hip_runtime.h>
#include <hip/hip_bf16.h>
#include <math.h>

#define LATENT 256
#define HIDDEN 512
#define NFD    64
#define MAXN   50
#define BATCH  128
#define NPAIR  2450   // 50*49
#define PTILE  64
#define NTILES 39     // ceil(2450/64)

typedef __attribute__((ext_vector_type(8))) _Float16 f16x8;
typedef __attribute__((ext_vector_type(4))) float f32x4;
typedef __attribute__((ext_vector_type(4))) unsigned int u32x4;

__device__ __forceinline__ float sigmoidf_(float x) {
    return 1.0f / (1.0f + expf(-x));
}
__device__ __forceinline__ f16x8 build_e1(f16x8 ui, f16x8 uj) {
    f16x8 s = ui + uj;
    return __builtin_elementwise_max(s, (f16x8)(_Float16)0);
}
__device__ __forceinline__ u32x4 pack8(float4 a, float4 b) {
    f16x8 h;
    h[0] = (_Float16)a.x; h[1] = (_Float16)a.y;
    h[2] = (_Float16)a.z; h[3] = (_Float16)a.w;
    h[4] = (_Float16)b.x; h[5] = (_Float16)b.y;
    h[6] = (_Float16)b.z; h[7] = (_Float16)b.w;
    return __builtin_bit_cast(u32x4, h);
}

// ---------------------------------------------------------------------------
// K1 prologue, grid (272, 4). Roles by blockIdx.x:
//  x<16     : fp32 gemm 32x64 tile (m0=32*y): h1h fp16 (n0<512) / Abc (n0>=512)
//  16<=x<32 : E2 -> E2t chunk-major fp16 [kc 0-63][256 g][8]
//  x>=32    : cvts: W2->W2t chunk-major [kc][512][8];
//             W3->W3t node-chunk-major [node][kc][64][8];
//             E1i/E1j -> linear [512 h][64 k] fp16
// ---------------------------------------------------------------------------
__global__ __launch_bounds__(256) void prologue_a(
    const float* __restrict__ z,
    const float* __restrict__ W1, const float* __restrict__ b1,
    const float* __restrict__ E1, const float* __restrict__ c1,
    const float* __restrict__ E2, const float* __restrict__ W2,
    const float* __restrict__ W3,
    unsigned short* __restrict__ E2t,
    unsigned short* __restrict__ W2t,
    unsigned short* __restrict__ W3t,
    unsigned short* __restrict__ E1ih,
    unsigned short* __restrict__ E1jh,
    unsigned short* __restrict__ h1h, float* __restrict__ Abc)
{
    const int tid = threadIdx.x;

    if (blockIdx.x >= 32) {   // conversions
        int slot = (blockIdx.x - 32) * 4 + blockIdx.y;   // 0..959
        int e = (slot * 256 + tid) * 8;
        float4 a, b;
        unsigned short* dst;
        if (e < 262144) {                 // W2 [512][512] -> W2t [kc][512][8]
            int row = e >> 9, k = e & 511;
            a = *(const float4*)&W2[e];
            b = *(const float4*)&W2[e + 4];
            dst = W2t + (((k >> 3) * 512 + row) << 3);
        } else if (e < 1900544) {         // W3 [3200][512] -> W3t [node][kc][64][8]
            int l = e - 262144;
            int grow = l >> 9, k = l & 511;
            int node = grow >> 6, row = grow & 63;
            a = *(const float4*)&W3[l];
            b = *(const float4*)&W3[l + 4];
            dst = W3t + node * 32768 + (((k >> 3) * 64 + row) << 3);
        } else if (e < 1933312) {         // E1i -> linear [512][64]
            int l = e - 1900544; int row = l >> 6, col = l & 63;
            a = *(const float4*)&E1[row * 384 + 256 + col];
            b = *(const float4*)&E1[row * 384 + 260 + col];
            dst = E1ih + l;
        } else {                          // E1j -> linear [512][64]
            int l = e - 1933312; int row = l >> 6, col = l & 63;
            a = *(const float4*)&E1[row * 384 + 320 + col];
            b = *(const float4*)&E1[row * 384 + 324 + col];
            dst = E1jh + l;
        }
        *(u32x4*)dst = pack8(a, b);
        return;
    }

    if (blockIdx.x >= 16) {   // E2 -> chunk-major fp16
        int idx = ((blockIdx.x - 16) * 4 + blockIdx.y) * 256 + tid;  // 16384
        int g  = idx & 255;
        int kc = idx >> 8;
        float4 a = *(const float4*)&E2[(size_t)g * 512 + kc * 8];
        float4 b = *(const float4*)&E2[(size_t)g * 512 + kc * 8 + 4];
        *(u32x4*)(E2t + (size_t)idx * 8) = pack8(a, b);
        return;
    }

    // fp32 NT gemm, 32x64 tile, 2x4/thread
    __shared__ __align__(16) float As[16][34];
    __shared__ __align__(16) float Bs[16][68];

    const int m0 = blockIdx.y * 32;
    const int n0 = blockIdx.x * 64;          // 0..1023
    const bool isE = n0 >= 512;
    const float* Bp = isE ? E1 + (size_t)(n0 - 512) * 384 : W1 + (size_t)n0 * 256;
    const int ldb = isE ? 384 : 256;

    const int sra = tid >> 3;        // 0..31
    const int kca = (tid & 7) * 2;
    const int srb = tid >> 2;        // 0..63
    const int kcb = (tid & 3) * 4;
    const int tx = tid & 15;
    const int ty = tid >> 4;         // 0..15

    float acc[2][4] = {};

    for (int k0 = 0; k0 < 256; k0 += 16) {
        float2 a2 = *(const float2*)&z[(size_t)(m0 + sra) * 256 + k0 + kca];
        As[kca][sra] = a2.x; As[kca + 1][sra] = a2.y;
        float4 b4 = *(const float4*)&Bp[(size_t)srb * ldb + k0 + kcb];
        Bs[kcb + 0][srb] = b4.x; Bs[kcb + 1][srb] = b4.y;
        Bs[kcb + 2][srb] = b4.z; Bs[kcb + 3][srb] = b4.w;
        __syncthreads();
        #pragma unroll
        for (int k = 0; k < 16; ++k) {
            float av[2], bv[4];
            av[0] = As[k][ty * 2]; av[1] = As[k][ty * 2 + 1];
            *(float4*)bv = *(const float4*)&Bs[k][tx * 4];
            #pragma unroll
            for (int r = 0; r < 2; ++r)
                #pragma unroll
                for (int c = 0; c < 4; ++c)
                    acc[r][c] = fmaf(av[r], bv[c], acc[r][c]);
        }
        __syncthreads();
    }

    #pragma unroll
    for (int r = 0; r < 2; ++r) {
        int gm = m0 + ty * 2 + r;
        #pragma unroll
        for (int c = 0; c < 4; ++c) {
            int gn = n0 + tx * 4 + c;
            if (isE) {
                int gl = gn - 512;
                Abc[(size_t)gm * 512 + gl] = acc[r][c] + c1[gl];
            } else {
                float v = fmaxf(acc[r][c] + b1[gn], 0.f);
                h1h[(size_t)gm * 512 + gn] =
                    __builtin_bit_cast(unsigned short, (_Float16)v);
            }
        }
    }
}

// ---------------------------------------------------------------------------
// K3': fused h2 + nf + Ui/Uj.  grid (50, 2): node = x, m0 = 64y. 512 thr.
//  Phase A (8 waves): h2s[64][512] = relu(h1h @ W2t^T + b2) in LDS.
//  Phase B (waves 0-3): nf = h2s @ W3t[node]^T + b3; sigmoid->out, fp16->nft.
//  Phase C (ALL 8 waves): wave w8 -> ij = w8>>2, w = w8&3 (half the work
//  per wave vs R14's 4-wave version; stores disjoint; nft read-only).
// ---------------------------------------------------------------------------
__global__ __launch_bounds__(512, 1) void nfu_gemm(
    const unsigned short* __restrict__ h1h,
    const unsigned short* __restrict__ W2t,   // [kc][512][8]
    const float* __restrict__ b2,
    const unsigned short* __restrict__ W3t,   // [node][kc][64][8]
    const float* __restrict__ b3,
    const unsigned short* __restrict__ E1ih,
    const unsigned short* __restrict__ E1jh,
    const float* __restrict__ Abc,
    float* __restrict__ outN,               // [128,3200] sigmoid
    unsigned short* __restrict__ Uih,       // [128*50,512]
    unsigned short* __restrict__ Ujh)
{
    __shared__ unsigned short As[2][64 * 32];          // 8KB h1 dbuf, swizzled
    __shared__ __align__(16) unsigned short h2s[64][520];  // 66.6KB
    __shared__ __align__(16) unsigned short nft[64][72];

    const int tid = threadIdx.x;
    const int lane = tid & 63;
    const int w8 = tid >> 6;     // 0..7
    const int w  = w8 & 3;       // phases B/C strip id
    const int ln = lane & 15;
    const int hi = lane >> 4;
    const int node = blockIdx.x;
    const int m0 = blockIdx.y * 64;

    // ---- phase A ----
    const int srow = (tid & 255) >> 2;
    const int sc   = tid & 3;
    const unsigned short* gA = h1h + (size_t)(m0 + srow) * 512 + sc * 8;
    const int swr = srow * 32 + ((sc ^ ((srow >> 1) & 3)) * 8);
    const int q   = hi ^ ((ln >> 1) & 3);
    const int ard = ln * 32 + q * 8;
    const unsigned short* bB = W2t + ((size_t)hi * 512 + 64 * w8 + ln) * 8;

    f32x4 acc[4][4] = {};
    f16x8 hN = {};
    if (tid < 256) {
        f16x8 h0 = *(const f16x8*)gA;
        *(f16x8*)&As[0][swr] = h0;
        hN = *(const f16x8*)(gA + 32);
    }
    f16x8 bf[4];
    #pragma unroll
    for (int ni = 0; ni < 4; ++ni)
        bf[ni] = *(const f16x8*)(bB + ni * 128);
    asm volatile("s_waitcnt lgkmcnt(0)\n\ts_barrier" ::: "memory");

    #pragma unroll
    for (int ks = 0; ks < 16; ++ks) {
        if (tid < 256 && ks < 15)
            *(f16x8*)&As[(ks + 1) & 1][swr] = hN;
        if (tid < 256 && ks < 14)
            hN = *(const f16x8*)(gA + 32 * (ks + 2));
        f16x8 af[4];
        #pragma unroll
        for (int mi = 0; mi < 4; ++mi)
            af[mi] = *(const f16x8*)&As[ks & 1][ard + mi * 512];
        __builtin_amdgcn_s_setprio(1);
        #pragma unroll
        for (int ni = 0; ni < 4; ++ni)
            #pragma unroll
            for (int mi = 0; mi < 4; ++mi)
                acc[mi][ni] = __builtin_amdgcn_mfma_f32_16x16x32_f16(
                    af[mi], bf[ni], acc[mi][ni], 0, 0, 0);
        __builtin_amdgcn_s_setprio(0);
        if (ks < 15) {
            #pragma unroll
            for (int ni = 0; ni < 4; ++ni)
                bf[ni] = *(const f16x8*)(bB + (size_t)(ks + 1) * 16384 + ni * 128);
            asm volatile("s_waitcnt lgkmcnt(0)\n\ts_barrier" ::: "memory");
        }
    }

    // epilogue A: relu + b2 -> h2s fp16
    #pragma unroll
    for (int ni = 0; ni < 4; ++ni) {
        int col = 64 * w8 + 16 * ni + ln;
        float bias = b2[col];
        #pragma unroll
        for (int mi = 0; mi < 4; ++mi)
            #pragma unroll
            for (int r = 0; r < 4; ++r) {
                float v = fmaxf(acc[mi][ni][r] + bias, 0.f);
                h2s[16 * mi + 4 * hi + r][col] =
                    __builtin_bit_cast(unsigned short, (_Float16)v);
            }
    }
    __syncthreads();

    // ---- phase B (waves 0-3): nf = h2s @ W3t[node]^T + b3 ----
    if (w8 < 4) {
        const unsigned short* bW3 = W3t + (size_t)node * 32768 + hi * 512 + ln * 8;
        f32x4 accB[4] = {};
        #pragma unroll
        for (int ks = 0; ks < 16; ++ks) {
            f16x8 af = *(const f16x8*)&h2s[16 * w + ln][ks * 32 + hi * 8];
            f16x8 bfB[4];
            #pragma unroll
            for (int ni = 0; ni < 4; ++ni)
                bfB[ni] = *(const f16x8*)(bW3 + ks * 2048 + ni * 128);
            #pragma unroll
            for (int ni = 0; ni < 4; ++ni)
                accB[ni] = __builtin_amdgcn_mfma_f32_16x16x32_f16(
                    af, bfB[ni], accB[ni], 0, 0, 0);
        }
        #pragma unroll
        for (int ni = 0; ni < 4; ++ni) {
            int gnl = 16 * ni + ln;
            int gng = node * 64 + gnl;
            float bias = b3[gng];
            #pragma unroll
            for (int r = 0; r < 4; ++r) {
                int bl = 16 * w + 4 * hi + r;
                float v = accB[ni][r] + bias;
                outN[(size_t)(m0 + bl) * 3200 + gng] = sigmoidf_(v);
                nft[bl][gnl] = __builtin_bit_cast(unsigned short, (_Float16)v);
            }
        }
    }
    __syncthreads();

    // ---- phase C (ALL 8 waves): wave w8 -> ij = w8>>2, strip w = w8&3 ----
    {
        const int ij = w8 >> 2;
        f16x8 af2[2][4];
        #pragma unroll
        for (int ks2 = 0; ks2 < 2; ++ks2)
            #pragma unroll
            for (int mi = 0; mi < 4; ++mi)
                af2[ks2][mi] = *(const f16x8*)&nft[16 * mi + ln][ks2 * 32 + hi * 8];

        const unsigned short* Ep = ij ? E1jh : E1ih;
        unsigned short* Ud = ij ? Ujh : Uih;
        #pragma unroll
        for (int half = 0; half < 2; ++half) {
            f32x4 acc2[4][4] = {};
            #pragma unroll
            for (int ks2 = 0; ks2 < 2; ++ks2) {
                f16x8 bf2[4];
                #pragma unroll
                for (int ni = 0; ni < 4; ++ni)
                    bf2[ni] = *(const f16x8*)(Ep +
                        (size_t)(128 * w + half * 64 + 16 * ni + ln) * 64 +
                        ks2 * 32 + hi * 8);
                #pragma unroll
                for (int ni = 0; ni < 4; ++ni)
                    #pragma unroll
                    for (int mi = 0; mi < 4; ++mi)
                        acc2[mi][ni] = __builtin_amdgcn_mfma_f32_16x16x32_f16(
                            af2[ks2][mi], bf2[ni], acc2[mi][ni], 0, 0, 0);
            }
            #pragma unroll
            for (int mi = 0; mi < 4; ++mi) {
                #pragma unroll
                for (int r = 0; r < 4; ++r) {
                    int batch = m0 + 16 * mi + 4 * hi + r;
                    #pragma unroll
                    for (int ni = 0; ni < 4; ++ni) {
                        int h = 128 * w + half * 64 + 16 * ni + ln;
                        float v = acc2[mi][ni][r];
                        if (ij == 0) v += Abc[(size_t)batch * 512 + h];
                        Ud[((size_t)batch * 50 + node) * 512 + h] =
                            __builtin_bit_cast(unsigned short, (_Float16)v);
                    }
                }
            }
        }
    }
}

// ---------------------------------------------------------------------------
// K4: MFMA edge kernel (R12 exact — best measured, 86 µs, reproduced 4x).
// Single bf register set (VGPR 64 arch + 64 acc), launch_bounds(256,4);
// B direct-from-global (chunk-major E2t), A dbuf LDS (swizzled);
// XCD-bijective 1D swizzle (4992 = 8 x 624).
// ---------------------------------------------------------------------------
__global__ __launch_bounds__(256, 4) void edge_mfma(
    const unsigned short* __restrict__ Ui,   // [B*50,512] fp16 (incl. Abc)
    const unsigned short* __restrict__ Uj,   // [B*50,512] fp16
    const unsigned short* __restrict__ E2t,  // [64 kc][256 g][8] fp16
    const float* __restrict__ c2,
    const float* __restrict__ E3,
    const float* __restrict__ c3p,
    float* __restrict__ outE)                // [B,2450]
{
    __shared__ unsigned short As[2][PTILE * 32];   // 8KB dbuf, swizzled
    __shared__ float c2_s[256], e3_s[256];
    __shared__ int   ii_s[PTILE], jj_s[PTILE];
    __shared__ float red[PTILE][5];

    // XCD-bijective swizzle: 4992 = 8 * 624
    const int gid = blockIdx.x;
    const int nid = (gid & 7) * 624 + (gid >> 3);
    const int b   = nid / NTILES;
    const int p0  = (nid - b * NTILES) * PTILE;

    const int tid = threadIdx.x;
    const int lane = tid & 63;
    const int wid  = tid >> 6;    // g quarter
    const int ln = lane & 15;
    const int hi = lane >> 4;

    c2_s[tid] = c2[tid];
    e3_s[tid] = E3[tid];
    if (tid < PTILE) {
        int p = p0 + tid;
        int i = 0, j = 0;
        if (p < NPAIR) {
            i = p / 49;
            int kk = p - i * 49;
            j = kk + (kk >= i ? 1 : 0);
        }
        ii_s[tid] = i;
        jj_s[tid] = j;
    }
    __syncthreads();

    const unsigned short* UiB = Ui + (size_t)b * MAXN * HIDDEN;
    const unsigned short* UjB = Uj + (size_t)b * MAXN * HIDDEN;

    // A staging: thread -> (row srow, chunk sc) of 64x32 tile
    const int srow = tid >> 2;
    const int sc   = tid & 3;
    const unsigned short* gUi = UiB + (size_t)ii_s[srow] * HIDDEN + sc * 8;
    const unsigned short* gUj = UjB + (size_t)jj_s[srow] * HIDDEN + sc * 8;
    const int swr = srow * 32 + ((sc ^ ((srow >> 1) & 3)) * 8);

    // A fragment read (swizzled): af[mi] at ard + mi*16*32
    const int q   = hi ^ ((ln >> 1) & 3);
    const int ard = ln * 32 + q * 8;

    // B fragment global base: + ks*8192 + ni*128
    const unsigned short* bB = E2t + ((size_t)hi * 256 + 64 * wid + ln) * 8;

    f32x4 acc[4][4] = {};

    // ---- prologue: A(0)->LDS; U(1)->regs; bf(0)->regs
    {
        f16x8 u0 = *(const f16x8*)gUi;
        f16x8 v0 = *(const f16x8*)gUj;
        *(f16x8*)&As[0][swr] = build_e1(u0, v0);
    }
    f16x8 uiN = *(const f16x8*)(gUi + 32);
    f16x8 ujN = *(const f16x8*)(gUj + 32);
    f16x8 bf[4];
    #pragma unroll
    for (int ni = 0; ni < 4; ++ni)
        bf[ni] = *(const f16x8*)(bB + ni * 128);
    asm volatile("s_waitcnt lgkmcnt(0)\n\ts_barrier" ::: "memory");

    #pragma unroll
    for (int ks = 0; ks < 16; ++ks) {
        // build + store A(ks+1) (consumes U(ks+1))
        if (ks < 15)
            *(f16x8*)&As[(ks + 1) & 1][swr] = build_e1(uiN, ujN);
        // prefetch U(ks+2)
        if (ks < 14) {
            uiN = *(const f16x8*)(gUi + 32 * (ks + 2));
            ujN = *(const f16x8*)(gUj + 32 * (ks + 2));
        }
        // af from LDS (post-barrier; 4 ds_read_b128)
        f16x8 af[4];
        #pragma unroll
        for (int mi = 0; mi < 4; ++mi)
            af[mi] = *(const f16x8*)&As[ks & 1][ard + mi * 512];
        // MFMA cluster (consumes bf(ks))
        __builtin_amdgcn_s_setprio(1);
        #pragma unroll
        for (int ni = 0; ni < 4; ++ni)
            #pragma unroll
            for (int mi = 0; mi < 4; ++mi)
                acc[mi][ni] = __builtin_amdgcn_mfma_f32_16x16x32_f16(
                    af[mi], bf[ni], acc[mi][ni], 0, 0, 0);
        __builtin_amdgcn_s_setprio(0);
        // reload bf for ks+1 (single set; issued after last MFMA read)
        if (ks < 15) {
            #pragma unroll
            for (int ni = 0; ni < 4; ++ni)
                bf[ni] = *(const f16x8*)(bB + (size_t)(ks + 1) * 8192 + ni * 128);
            asm volatile("s_waitcnt lgkmcnt(0)\n\ts_barrier" ::: "memory");
        }
    }

    // ---- epilogue
    const float c3v = c3p[0];
    #pragma unroll
    for (int mi = 0; mi < 4; ++mi) {
        #pragma unroll
        for (int r = 0; r < 4; ++r) {
            float part = 0.f;
            #pragma unroll
            for (int ni = 0; ni < 4; ++ni) {
                int g = 64 * wid + 16 * ni + ln;
                float v = fmaxf(acc[mi][ni][r] + c2_s[g], 0.f);
                part = fmaf(v, e3_s[g], part);
            }
            part += __shfl_xor(part, 1);
            part += __shfl_xor(part, 2);
            part += __shfl_xor(part, 4);
            part += __shfl_xor(part, 8);
            if (ln == 0) red[16 * mi + 4 * hi + r][wid] = part;
        }
    }
    __syncthreads();

    if (tid < PTILE) {
        int p = p0 + tid;
        if (p < NPAIR) {
            float s = red[tid][0] + red[tid][1] + red[tid][2] + red[tid][3] + c3v;
            outE[(size_t)b * NPAIR + p] = sigmoidf_(s);
        }
    }
}

// ---------------------------------------------------------------------------
extern "C" void kernel_launch(void* const* d_in, const int* in_sizes, int n_in,
                              void* d_out, int out_size, void* d_ws, size_t ws_size,
                              hipStream_t stream)
{
    const float* z  = (const float*)d_in[0];
    const float* W1 = (const float*)d_in[1];
    const float* b1 = (const float*)d_in[2];
    const float* W2 = (const float*)d_in[3];
    const float* b2 = (const float*)d_in[4];
    const float* W3 = (const float*)d_in[5];
    const float* b3 = (const float*)d_in[6];
    const float* E1 = (const float*)d_in[7];
    const float* c1 = (const float*)d_in[8];
    const float* E2 = (const float*)d_in[9];
    const float* c2 = (const float*)d_in[10];
    const float* E3 = (const float*)d_in[11];
    const float* c3 = (const float*)d_in[12];

    float* out = (float*)d_out;
    float* ws  = (float*)d_ws;

    // workspace layout
    float* Abc = ws;                                        // 65536 f32
    unsigned short* h1h  = (unsigned short*)(Abc + 65536);  // 65536
    unsigned short* W2t  = h1h + 65536;                     // 262144
    unsigned short* W3t  = W2t + 262144;                    // 1638400
    unsigned short* E1ih = W3t + 1638400;                   // 32768
    unsigned short* E1jh = E1ih + 32768;                    // 32768
    unsigned short* E2t  = E1jh + 32768;                    // 131072
    unsigned short* Uih  = E2t + 131072;                    // 3276800
    unsigned short* Ujh  = Uih + 3276800;                   // 3276800

    dim3 blk(256);

    // K1: h1h, Abc, E2t, W2t, W3t, E1ih, E1jh
    prologue_a<<<dim3(272, 4), blk, 0, stream>>>(
        z, W1, b1, E1, c1, E2, W2, W3, E2t, W2t, W3t, E1ih, E1jh, h1h, Abc);

    // K3': fused h2 + nf (sigmoid->out) + Ui/Uj (phase-C on all 8 waves)
    nfu_gemm<<<dim3(50, 2), dim3(512), 0, stream>>>(
        h1h, W2t, b2, W3t, b3, E1ih, E1jh, Abc, out, Uih, Ujh);

    // K4: fused edge MLP (1D grid, XCD-swizzled)
    edge_mfma<<<dim3(NTILES * BATCH), blk, 0, stream>>>(
        Uih, Ujh, E2t, c2, E3, c3, out + BATCH * MAXN * NFD);
}

// Round 18
// 124.746 us; speedup vs baseline: 1.2352x; 1.1724x over previous
//
#include <hip/hip_runtime.h>
#include <hip/hip_bf16.h>
#include <math.h>

#define LATENT 256
#define HIDDEN 512
#define NFD    64
#define MAXN   50
#define BATCH  128
#define NPAIR  2450   // 50*49
#define PTILE  64
#define NTILES 39     // ceil(2450/64)

typedef __attribute__((ext_vector_type(8))) _Float16 f16x8;
typedef __attribute__((ext_vector_type(4))) float f32x4;
typedef __attribute__((ext_vector_type(4))) unsigned int u32x4;

__device__ __forceinline__ float sigmoidf_(float x) {
    return 1.0f / (1.0f + expf(-x));
}
__device__ __forceinline__ f16x8 build_e1(f16x8 ui, f16x8 uj) {
    f16x8 s = ui + uj;
    return __builtin_elementwise_max(s, (f16x8)(_Float16)0);
}
__device__ __forceinline__ u32x4 pack8(float4 a, float4 b) {
    f16x8 h;
    h[0] = (_Float16)a.x; h[1] = (_Float16)a.y;
    h[2] = (_Float16)a.z; h[3] = (_Float16)a.w;
    h[4] = (_Float16)b.x; h[5] = (_Float16)b.y;
    h[6] = (_Float16)b.z; h[7] = (_Float16)b.w;
    return __builtin_bit_cast(u32x4, h);
}

// ---------------------------------------------------------------------------
// K1 prologue, grid (272, 4). Roles by blockIdx.x:
//  x<16     : fp32 gemm 32x64 tile (m0=32*y): h1h fp16 (n0<512) / Abc (n0>=512)
//  16<=x<32 : E2 -> E2t chunk-major fp16 [kc 0-63][256 g][8]
//  x>=32    : cvts: W2->W2t chunk-major [kc][512][8];
//             W3->W3t node-chunk-major [node][kc][64][8];
//             E1i/E1j -> linear [512 h][64 k] fp16
// ---------------------------------------------------------------------------
__global__ __launch_bounds__(256) void prologue_a(
    const float* __restrict__ z,
    const float* __restrict__ W1, const float* __restrict__ b1,
    const float* __restrict__ E1, const float* __restrict__ c1,
    const float* __restrict__ E2, const float* __restrict__ W2,
    const float* __restrict__ W3,
    unsigned short* __restrict__ E2t,
    unsigned short* __restrict__ W2t,
    unsigned short* __restrict__ W3t,
    unsigned short* __restrict__ E1ih,
    unsigned short* __restrict__ E1jh,
    unsigned short* __restrict__ h1h, float* __restrict__ Abc)
{
    const int tid = threadIdx.x;

    if (blockIdx.x >= 32) {   // conversions
        int slot = (blockIdx.x - 32) * 4 + blockIdx.y;   // 0..959
        int e = (slot * 256 + tid) * 8;
        float4 a, b;
        unsigned short* dst;
        if (e < 262144) {                 // W2 [512][512] -> W2t [kc][512][8]
            int row = e >> 9, k = e & 511;
            a = *(const float4*)&W2[e];
            b = *(const float4*)&W2[e + 4];
            dst = W2t + (((k >> 3) * 512 + row) << 3);
        } else if (e < 1900544) {         // W3 [3200][512] -> W3t [node][kc][64][8]
            int l = e - 262144;
            int grow = l >> 9, k = l & 511;
            int node = grow >> 6, row = grow & 63;
            a = *(const float4*)&W3[l];
            b = *(const float4*)&W3[l + 4];
            dst = W3t + node * 32768 + (((k >> 3) * 64 + row) << 3);
        } else if (e < 1933312) {         // E1i -> linear [512][64]
            int l = e - 1900544; int row = l >> 6, col = l & 63;
            a = *(const float4*)&E1[row * 384 + 256 + col];
            b = *(const float4*)&E1[row * 384 + 260 + col];
            dst = E1ih + l;
        } else {                          // E1j -> linear [512][64]
            int l = e - 1933312; int row = l >> 6, col = l & 63;
            a = *(const float4*)&E1[row * 384 + 320 + col];
            b = *(const float4*)&E1[row * 384 + 324 + col];
            dst = E1jh + l;
        }
        *(u32x4*)dst = pack8(a, b);
        return;
    }

    if (blockIdx.x >= 16) {   // E2 -> chunk-major fp16
        int idx = ((blockIdx.x - 16) * 4 + blockIdx.y) * 256 + tid;  // 16384
        int g  = idx & 255;
        int kc = idx >> 8;
        float4 a = *(const float4*)&E2[(size_t)g * 512 + kc * 8];
        float4 b = *(const float4*)&E2[(size_t)g * 512 + kc * 8 + 4];
        *(u32x4*)(E2t + (size_t)idx * 8) = pack8(a, b);
        return;
    }

    // fp32 NT gemm, 32x64 tile, 2x4/thread
    __shared__ __align__(16) float As[16][34];
    __shared__ __align__(16) float Bs[16][68];

    const int m0 = blockIdx.y * 32;
    const int n0 = blockIdx.x * 64;          // 0..1023
    const bool isE = n0 >= 512;
    const float* Bp = isE ? E1 + (size_t)(n0 - 512) * 384 : W1 + (size_t)n0 * 256;
    const int ldb = isE ? 384 : 256;

    const int sra = tid >> 3;        // 0..31
    const int kca = (tid & 7) * 2;
    const int srb = tid >> 2;        // 0..63
    const int kcb = (tid & 3) * 4;
    const int tx = tid & 15;
    const int ty = tid >> 4;         // 0..15

    float acc[2][4] = {};

    for (int k0 = 0; k0 < 256; k0 += 16) {
        float2 a2 = *(const float2*)&z[(size_t)(m0 + sra) * 256 + k0 + kca];
        As[kca][sra] = a2.x; As[kca + 1][sra] = a2.y;
        float4 b4 = *(const float4*)&Bp[(size_t)srb * ldb + k0 + kcb];
        Bs[kcb + 0][srb] = b4.x; Bs[kcb + 1][srb] = b4.y;
        Bs[kcb + 2][srb] = b4.z; Bs[kcb + 3][srb] = b4.w;
        __syncthreads();
        #pragma unroll
        for (int k = 0; k < 16; ++k) {
            float av[2], bv[4];
            av[0] = As[k][ty * 2]; av[1] = As[k][ty * 2 + 1];
            *(float4*)bv = *(const float4*)&Bs[k][tx * 4];
            #pragma unroll
            for (int r = 0; r < 2; ++r)
                #pragma unroll
                for (int c = 0; c < 4; ++c)
                    acc[r][c] = fmaf(av[r], bv[c], acc[r][c]);
        }
        __syncthreads();
    }

    #pragma unroll
    for (int r = 0; r < 2; ++r) {
        int gm = m0 + ty * 2 + r;
        #pragma unroll
        for (int c = 0; c < 4; ++c) {
            int gn = n0 + tx * 4 + c;
            if (isE) {
                int gl = gn - 512;
                Abc[(size_t)gm * 512 + gl] = acc[r][c] + c1[gl];
            } else {
                float v = fmaxf(acc[r][c] + b1[gn], 0.f);
                h1h[(size_t)gm * 512 + gn] =
                    __builtin_bit_cast(unsigned short, (_Float16)v);
            }
        }
    }
}

// ---------------------------------------------------------------------------
// K3': fused h2 + nf + Ui/Uj.  grid (50, 2): node = x, m0 = 64y. 512 thr.
//  Phase A (8 waves): h2s[64][512] = relu(h1h[m0-slice] @ W2t^T + b2) in LDS.
//  Phase B (waves 0-3): nf tile = h2s @ W3t[node]^T + b3; sigmoid -> out,
//    fp16 -> nft.
//  Phase C (waves 0-3): Ui/Uj from nft @ E1i/E1j (R14-exact).
// ---------------------------------------------------------------------------
__global__ __launch_bounds__(512, 1) void nfu_gemm(
    const unsigned short* __restrict__ h1h,
    const unsigned short* __restrict__ W2t,   // [kc][512][8]
    const float* __restrict__ b2,
    const unsigned short* __restrict__ W3t,   // [node][kc][64][8]
    const float* __restrict__ b3,
    const unsigned short* __restrict__ E1ih,
    const unsigned short* __restrict__ E1jh,
    const float* __restrict__ Abc,
    float* __restrict__ outN,               // [128,3200] sigmoid
    unsigned short* __restrict__ Uih,       // [128*50,512]
    unsigned short* __restrict__ Ujh)
{
    __shared__ unsigned short As[2][64 * 32];          // 8KB h1 dbuf, swizzled
    __shared__ __align__(16) unsigned short h2s[64][520];  // 66.6KB
    __shared__ __align__(16) unsigned short nft[64][72];

    const int tid = threadIdx.x;
    const int lane = tid & 63;
    const int w8 = tid >> 6;     // 0..7
    const int w  = w8 & 3;       // phases B/C wave id
    const int ln = lane & 15;
    const int hi = lane >> 4;
    const int node = blockIdx.x;
    const int m0 = blockIdx.y * 64;

    // ---- phase A ----
    const int srow = (tid & 255) >> 2;
    const int sc   = tid & 3;
    const unsigned short* gA = h1h + (size_t)(m0 + srow) * 512 + sc * 8;
    const int swr = srow * 32 + ((sc ^ ((srow >> 1) & 3)) * 8);
    const int q   = hi ^ ((ln >> 1) & 3);
    const int ard = ln * 32 + q * 8;
    const unsigned short* bB = W2t + ((size_t)hi * 512 + 64 * w8 + ln) * 8;

    f32x4 acc[4][4] = {};
    f16x8 hN = {};
    if (tid < 256) {
        f16x8 h0 = *(const f16x8*)gA;
        *(f16x8*)&As[0][swr] = h0;
        hN = *(const f16x8*)(gA + 32);
    }
    f16x8 bf[4];
    #pragma unroll
    for (int ni = 0; ni < 4; ++ni)
        bf[ni] = *(const f16x8*)(bB + ni * 128);
    asm volatile("s_waitcnt lgkmcnt(0)\n\ts_barrier" ::: "memory");

    #pragma unroll
    for (int ks = 0; ks < 16; ++ks) {
        if (tid < 256 && ks < 15)
            *(f16x8*)&As[(ks + 1) & 1][swr] = hN;
        if (tid < 256 && ks < 14)
            hN = *(const f16x8*)(gA + 32 * (ks + 2));
        f16x8 af[4];
        #pragma unroll
        for (int mi = 0; mi < 4; ++mi)
            af[mi] = *(const f16x8*)&As[ks & 1][ard + mi * 512];
        __builtin_amdgcn_s_setprio(1);
        #pragma unroll
        for (int ni = 0; ni < 4; ++ni)
            #pragma unroll
            for (int mi = 0; mi < 4; ++mi)
                acc[mi][ni] = __builtin_amdgcn_mfma_f32_16x16x32_f16(
                    af[mi], bf[ni], acc[mi][ni], 0, 0, 0);
        __builtin_amdgcn_s_setprio(0);
        if (ks < 15) {
            #pragma unroll
            for (int ni = 0; ni < 4; ++ni)
                bf[ni] = *(const f16x8*)(bB + (size_t)(ks + 1) * 16384 + ni * 128);
            asm volatile("s_waitcnt lgkmcnt(0)\n\ts_barrier" ::: "memory");
        }
    }

    // epilogue A: relu + b2 -> h2s fp16
    #pragma unroll
    for (int ni = 0; ni < 4; ++ni) {
        int col = 64 * w8 + 16 * ni + ln;
        float bias = b2[col];
        #pragma unroll
        for (int mi = 0; mi < 4; ++mi)
            #pragma unroll
            for (int r = 0; r < 4; ++r) {
                float v = fmaxf(acc[mi][ni][r] + bias, 0.f);
                h2s[16 * mi + 4 * hi + r][col] =
                    __builtin_bit_cast(unsigned short, (_Float16)v);
            }
    }
    __syncthreads();

    // ---- phase B (waves 0-3): nf = h2s @ W3t[node]^T + b3 ----
    if (w8 < 4) {
        const unsigned short* bW3 = W3t + (size_t)node * 32768 + hi * 512 + ln * 8;
        f32x4 accB[4] = {};
        #pragma unroll
        for (int ks = 0; ks < 16; ++ks) {
            f16x8 af = *(const f16x8*)&h2s[16 * w + ln][ks * 32 + hi * 8];
            f16x8 bfB[4];
            #pragma unroll
            for (int ni = 0; ni < 4; ++ni)
                bfB[ni] = *(const f16x8*)(bW3 + ks * 2048 + ni * 128);
            #pragma unroll
            for (int ni = 0; ni < 4; ++ni)
                accB[ni] = __builtin_amdgcn_mfma_f32_16x16x32_f16(
                    af, bfB[ni], accB[ni], 0, 0, 0);
        }
        #pragma unroll
        for (int ni = 0; ni < 4; ++ni) {
            int gnl = 16 * ni + ln;
            int gng = node * 64 + gnl;
            float bias = b3[gng];
            #pragma unroll
            for (int r = 0; r < 4; ++r) {
                int bl = 16 * w + 4 * hi + r;
                float v = accB[ni][r] + bias;
                outN[(size_t)(m0 + bl) * 3200 + gng] = sigmoidf_(v);
                nft[bl][gnl] = __builtin_bit_cast(unsigned short, (_Float16)v);
            }
        }
    }
    __syncthreads();

    // ---- phase C (waves 0-3): Ui/Uj (R14-exact) ----
    if (w8 < 4) {
        f16x8 af2[2][4];
        #pragma unroll
        for (int ks2 = 0; ks2 < 2; ++ks2)
            #pragma unroll
            for (int mi = 0; mi < 4; ++mi)
                af2[ks2][mi] = *(const f16x8*)&nft[16 * mi + ln][ks2 * 32 + hi * 8];

        #pragma unroll
        for (int ij = 0; ij < 2; ++ij) {
            const unsigned short* Ep = ij ? E1jh : E1ih;
            unsigned short* Ud = ij ? Ujh : Uih;
            #pragma unroll
            for (int half = 0; half < 2; ++half) {
                f32x4 acc2[4][4] = {};
                #pragma unroll
                for (int ks2 = 0; ks2 < 2; ++ks2) {
                    f16x8 bf2[4];
                    #pragma unroll
                    for (int ni = 0; ni < 4; ++ni)
                        bf2[ni] = *(const f16x8*)(Ep +
                            (size_t)(128 * w + half * 64 + 16 * ni + ln) * 64 +
                            ks2 * 32 + hi * 8);
                    #pragma unroll
                    for (int ni = 0; ni < 4; ++ni)
                        #pragma unroll
                        for (int mi = 0; mi < 4; ++mi)
                            acc2[mi][ni] = __builtin_amdgcn_mfma_f32_16x16x32_f16(
                                af2[ks2][mi], bf2[ni], acc2[mi][ni], 0, 0, 0);
                }
                #pragma unroll
                for (int mi = 0; mi < 4; ++mi) {
                    #pragma unroll
                    for (int r = 0; r < 4; ++r) {
                        int batch = m0 + 16 * mi + 4 * hi + r;
                        #pragma unroll
                        for (int ni = 0; ni < 4; ++ni) {
                            int h = 128 * w + half * 64 + 16 * ni + ln;
                            float v = acc2[mi][ni][r];
                            if (ij == 0) v += Abc[(size_t)batch * 512 + h];
                            Ud[((size_t)batch * 50 + node) * 512 + h] =
                                __builtin_bit_cast(unsigned short, (_Float16)v);
                        }
                    }
                }
            }
        }
    }
}

// ---------------------------------------------------------------------------
// K4: MFMA edge kernel (R12 exact — best measured, 86 µs, reproduced 5x).
// Single bf register set (VGPR 64 arch + 64 acc), launch_bounds(256,4);
// B direct-from-global (chunk-major E2t), A dbuf LDS (swizzled);
// XCD-bijective 1D swizzle (4992 = 8 x 624).
// ---------------------------------------------------------------------------
__global__ __launch_bounds__(256, 4) void edge_mfma(
    const unsigned short* __restrict__ Ui,   // [B*50,512] fp16 (incl. Abc)
    const unsigned short* __restrict__ Uj,   // [B*50,512] fp16
    const unsigned short* __restrict__ E2t,  // [64 kc][256 g][8] fp16
    const float* __restrict__ c2,
    const float* __restrict__ E3,
    const float* __restrict__ c3p,
    float* __restrict__ outE)                // [B,2450]
{
    __shared__ unsigned short As[2][PTILE * 32];   // 8KB dbuf, swizzled
    __shared__ float c2_s[256], e3_s[256];
    __shared__ int   ii_s[PTILE], jj_s[PTILE];
    __shared__ float red[PTILE][5];

    // XCD-bijective swizzle: 4992 = 8 * 624
    const int gid = blockIdx.x;
    const int nid = (gid & 7) * 624 + (gid >> 3);
    const int b   = nid / NTILES;
    const int p0  = (nid - b * NTILES) * PTILE;

    const int tid = threadIdx.x;
    const int lane = tid & 63;
    const int wid  = tid >> 6;    // g quarter
    const int ln = lane & 15;
    const int hi = lane >> 4;

    c2_s[tid] = c2[tid];
    e3_s[tid] = E3[tid];
    if (tid < PTILE) {
        int p = p0 + tid;
        int i = 0, j = 0;
        if (p < NPAIR) {
            i = p / 49;
            int kk = p - i * 49;
            j = kk + (kk >= i ? 1 : 0);
        }
        ii_s[tid] = i;
        jj_s[tid] = j;
    }
    __syncthreads();

    const unsigned short* UiB = Ui + (size_t)b * MAXN * HIDDEN;
    const unsigned short* UjB = Uj + (size_t)b * MAXN * HIDDEN;

    // A staging: thread -> (row srow, chunk sc) of 64x32 tile
    const int srow = tid >> 2;
    const int sc   = tid & 3;
    const unsigned short* gUi = UiB + (size_t)ii_s[srow] * HIDDEN + sc * 8;
    const unsigned short* gUj = UjB + (size_t)jj_s[srow] * HIDDEN + sc * 8;
    const int swr = srow * 32 + ((sc ^ ((srow >> 1) & 3)) * 8);

    // A fragment read (swizzled): af[mi] at ard + mi*16*32
    const int q   = hi ^ ((ln >> 1) & 3);
    const int ard = ln * 32 + q * 8;

    // B fragment global base: + ks*8192 + ni*128
    const unsigned short* bB = E2t + ((size_t)hi * 256 + 64 * wid + ln) * 8;

    f32x4 acc[4][4] = {};

    // ---- prologue: A(0)->LDS; U(1)->regs; bf(0)->regs
    {
        f16x8 u0 = *(const f16x8*)gUi;
        f16x8 v0 = *(const f16x8*)gUj;
        *(f16x8*)&As[0][swr] = build_e1(u0, v0);
    }
    f16x8 uiN = *(const f16x8*)(gUi + 32);
    f16x8 ujN = *(const f16x8*)(gUj + 32);
    f16x8 bf[4];
    #pragma unroll
    for (int ni = 0; ni < 4; ++ni)
        bf[ni] = *(const f16x8*)(bB + ni * 128);
    asm volatile("s_waitcnt lgkmcnt(0)\n\ts_barrier" ::: "memory");

    #pragma unroll
    for (int ks = 0; ks < 16; ++ks) {
        // build + store A(ks+1) (consumes U(ks+1))
        if (ks < 15)
            *(f16x8*)&As[(ks + 1) & 1][swr] = build_e1(uiN, ujN);
        // prefetch U(ks+2)
        if (ks < 14) {
            uiN = *(const f16x8*)(gUi + 32 * (ks + 2));
            ujN = *(const f16x8*)(gUj + 32 * (ks + 2));
        }
        // af from LDS (post-barrier; 4 ds_read_b128)
        f16x8 af[4];
        #pragma unroll
        for (int mi = 0; mi < 4; ++mi)
            af[mi] = *(const f16x8*)&As[ks & 1][ard + mi * 512];
        // MFMA cluster (consumes bf(ks))
        __builtin_amdgcn_s_setprio(1);
        #pragma unroll
        for (int ni = 0; ni < 4; ++ni)
            #pragma unroll
            for (int mi = 0; mi < 4; ++mi)
                acc[mi][ni] = __builtin_amdgcn_mfma_f32_16x16x32_f16(
                    af[mi], bf[ni], acc[mi][ni], 0, 0, 0);
        __builtin_amdgcn_s_setprio(0);
        // reload bf for ks+1 (single set; issued after last MFMA read)
        if (ks < 15) {
            #pragma unroll
            for (int ni = 0; ni < 4; ++ni)
                bf[ni] = *(const f16x8*)(bB + (size_t)(ks + 1) * 8192 + ni * 128);
            asm volatile("s_waitcnt lgkmcnt(0)\n\ts_barrier" ::: "memory");
        }
    }

    // ---- epilogue
    const float c3v = c3p[0];
    #pragma unroll
    for (int mi = 0; mi < 4; ++mi) {
        #pragma unroll
        for (int r = 0; r < 4; ++r) {
            float part = 0.f;
            #pragma unroll
            for (int ni = 0; ni < 4; ++ni) {
                int g = 64 * wid + 16 * ni + ln;
                float v = fmaxf(acc[mi][ni][r] + c2_s[g], 0.f);
                part = fmaf(v, e3_s[g], part);
            }
            part += __shfl_xor(part, 1);
            part += __shfl_xor(part, 2);
            part += __shfl_xor(part, 4);
            part += __shfl_xor(part, 8);
            if (ln == 0) red[16 * mi + 4 * hi + r][wid] = part;
        }
    }
    __syncthreads();

    if (tid < PTILE) {
        int p = p0 + tid;
        if (p < NPAIR) {
            float s = red[tid][0] + red[tid][1] + red[tid][2] + red[tid][3] + c3v;
            outE[(size_t)b * NPAIR + p] = sigmoidf_(s);
        }
    }
}

// ---------------------------------------------------------------------------
extern "C" void kernel_launch(void* const* d_in, const int* in_sizes, int n_in,
                              void* d_out, int out_size, void* d_ws, size_t ws_size,
                              hipStream_t stream)
{
    const float* z  = (const float*)d_in[0];
    const float* W1 = (const float*)d_in[1];
    const float* b1 = (const float*)d_in[2];
    const float* W2 = (const float*)d_in[3];
    const float* b2 = (const float*)d_in[4];
    const float* W3 = (const float*)d_in[5];
    const float* b3 = (const float*)d_in[6];
    const float* E1 = (const float*)d_in[7];
    const float* c1 = (const float*)d_in[8];
    const float* E2 = (const float*)d_in[9];
    const float* c2 = (const float*)d_in[10];
    const float* E3 = (const float*)d_in[11];
    const float* c3 = (const float*)d_in[12];

    float* out = (float*)d_out;
    float* ws  = (float*)d_ws;

    // workspace layout
    float* Abc = ws;                                        // 65536 f32
    unsigned short* h1h  = (unsigned short*)(Abc + 65536);  // 65536
    unsigned short* W2t  = h1h + 65536;                     // 262144
    unsigned short* W3t  = W2t + 262144;                    // 1638400
    unsigned short* E1ih = W3t + 1638400;                   // 32768
    unsigned short* E1jh = E1ih + 32768;                    // 32768
    unsigned short* E2t  = E1jh + 32768;                    // 131072
    unsigned short* Uih  = E2t + 131072;                    // 3276800
    unsigned short* Ujh  = Uih + 3276800;                   // 3276800

    dim3 blk(256);

    // K1: h1h, Abc, E2t, W2t, W3t, E1ih, E1jh
    prologue_a<<<dim3(272, 4), blk, 0, stream>>>(
        z, W1, b1, E1, c1, E2, W2, W3, E2t, W2t, W3t, E1ih, E1jh, h1h, Abc);

    // K3': fused h2 + nf (sigmoid->out) + Ui/Uj
    nfu_gemm<<<dim3(50, 2), dim3(512), 0, stream>>>(
        h1h, W2t, b2, W3t, b3, E1ih, E1jh, Abc, out, Uih, Ujh);

    // K4: fused edge MLP (1D grid, XCD-swizzled)
    edge_mfma<<<dim3(NTILES * BATCH), blk, 0, stream>>>(
        Uih, Ujh, E2t, c2, E3, c3, out + BATCH * MAXN * NFD);
}